// Round 10
// baseline (256.349 us; speedup 1.0000x reference)
//
#include <hip/hip_runtime.h>
#include <stdint.h>

#define Bn 16
#define Sn 2048
#define Dn 128
#define QBLK 64
#define KVBLK 64
#define NTHR 256

typedef __attribute__((ext_vector_type(4))) float f32x4;
typedef __attribute__((ext_vector_type(16))) float f32x16;
typedef __attribute__((ext_vector_type(8))) short bf16x8;   // 8 bf16 = 4 VGPRs
typedef __attribute__((ext_vector_type(2))) unsigned int u32x2;

// LDS: single shared tile buffer, 34304 B:
//  K  : [64] rows stride 264 B  byte(k,d) = k*264 + 2d   (2-way banks, free)
//  VT : [128] rows stride 136 B byte(d,k) = d*136 + 2k   (2-way banks)
// Epilogue exchange regions overlay the buffer (post-loop only): qw*16896.
#define KSTRIDE 264
#define VTOFF 16896
#define VSTRIDE 136
#define SMEM_BYTES 34304

__device__ __forceinline__ uint32_t f2bf_u(float f) {   // fp32 -> bf16, round-nearest-away
  return (__float_as_uint(f) + 0x8000u) >> 16;
}
__device__ __forceinline__ uint32_t pk2(float a, float b) {
  return f2bf_u(a) | (f2bf_u(b) << 16);
}

// SPLIT: blockIdx.z = KV half; emit UNNORMALIZED partial + (m,l). Else direct O.
template <bool SPLIT>
__global__ __launch_bounds__(NTHR, 4) void attn_fwd(
    const float* __restrict__ Q, const float* __restrict__ K,
    const float* __restrict__ V, float* __restrict__ O0,
    float* __restrict__ O1, float2* __restrict__ ml0,
    float2* __restrict__ ml1) {
  __shared__ uint4 smem_[SMEM_BYTES / 16];
  char* smem = (char*)smem_;

  const int tid = threadIdx.x;
  const int lane = tid & 63;
  const int w = tid >> 6;        // wave 0..3
  const int qw = w & 1;          // q sub-tile (32 rows)
  const int h = w >> 1;          // k sub-range of tile (32 rows)
  const int hi = lane >> 5;      // half-wave 0/1
  const int ql = lane & 31;      // q / k-row / d-row selector
  const int b = blockIdx.y;
  const int q0 = blockIdx.x * QBLK;
  const int qg = q0 + qw * 32 + ql;
  const int vm = tid & 127;      // V staging: owned column
  const int vkh = tid >> 7;      // V staging: k-half 0/1
  const int kvh = SPLIT ? blockIdx.z : 0;
  const int nt = SPLIT ? 16 : 32;
  const int kvbase = kvh * (Sn / 2);

  // ---- Q in registers: B-operand of swapped QK^T. col=q=lane&31, kd=8*hi+j ----
  const float qscale = 0.08838834764831845f * 1.44269504088896340736f; // 1/sqrt(128)*log2e
  bf16x8 qf[8];
  {
    const float* qrow = Q + (size_t)(b * Sn + qg) * Dn;
#pragma unroll
    for (int dk = 0; dk < 8; ++dk) {
      const int d0 = dk * 16 + hi * 8;
      const float4 a = *(const float4*)(qrow + d0);
      const float4 d = *(const float4*)(qrow + d0 + 4);
      bf16x8 q8;
      q8[0] = (short)f2bf_u(a.x * qscale); q8[1] = (short)f2bf_u(a.y * qscale);
      q8[2] = (short)f2bf_u(a.z * qscale); q8[3] = (short)f2bf_u(a.w * qscale);
      q8[4] = (short)f2bf_u(d.x * qscale); q8[5] = (short)f2bf_u(d.y * qscale);
      q8[6] = (short)f2bf_u(d.z * qscale); q8[7] = (short)f2bf_u(d.w * qscale);
      qf[dk] = q8;
    }
  }

  f32x16 o[4];
#pragma unroll
  for (int dt = 0; dt < 4; ++dt) {
#pragma unroll
    for (int j = 0; j < 16; ++j) o[dt][j] = 0.f;
  }
  float m_r = -1.0e30f, l_r = 0.f;

  const float4* Kg4 = (const float4*)(K + (size_t)b * Sn * Dn);
  const float* Vg_base = V + (size_t)b * Sn * Dn;

#define STAGE(kv_)                                                             \
  {                                                                            \
    const int kvrow4 = (kv_) * (Dn / 4);                                       \
    _Pragma("unroll") for (int it = 0; it < 8; ++it) {                         \
      const int gr = it * NTHR + tid;                                          \
      const int k = gr >> 5, dg = gr & 31;                                     \
      float4 kvv = Kg4[kvrow4 + k * 32 + dg];                                  \
      u32x2 wv;                                                                \
      wv.x = pk2(kvv.x, kvv.y);                                                \
      wv.y = pk2(kvv.z, kvv.w);                                                \
      *(u32x2*)(smem + k * KSTRIDE + dg * 8) = wv;                             \
    }                                                                          \
    const float* Vg = Vg_base + (size_t)(kv_)*Dn;                              \
    _Pragma("unroll") for (int i = 0; i < 4; ++i) {                            \
      const int k0 = vkh * 32 + i * 8;                                         \
      uint4 pk;                                                                \
      {                                                                        \
        float v0 = Vg[(k0 + 0) * Dn + vm], v1 = Vg[(k0 + 1) * Dn + vm];        \
        float v2 = Vg[(k0 + 2) * Dn + vm], v3 = Vg[(k0 + 3) * Dn + vm];        \
        float v4 = Vg[(k0 + 4) * Dn + vm], v5 = Vg[(k0 + 5) * Dn + vm];        \
        float v6 = Vg[(k0 + 6) * Dn + vm], v7 = Vg[(k0 + 7) * Dn + vm];        \
        pk.x = pk2(v0, v1); pk.y = pk2(v2, v3);                                \
        pk.z = pk2(v4, v5); pk.w = pk2(v6, v7);                                \
      }                                                                        \
      *(uint4*)(smem + VTOFF + vm * VSTRIDE + k0 * 2) = pk;                    \
    }                                                                          \
  }

  STAGE(kvbase)
  __syncthreads();

  for (int t = 0; t < nt; ++t) {
    // ---- swapped QK^T: S^T[k'][q], k' = this wave's 32-row k-subset ----
    f32x16 s;
#pragma unroll
    for (int j = 0; j < 16; ++j) s[j] = 0.f;
    __builtin_amdgcn_s_setprio(1);
#pragma unroll
    for (int dk = 0; dk < 8; ++dk) {
      bf16x8 a = *(const bf16x8*)(smem + (32 * h + ql) * KSTRIDE +
                                  dk * 32 + hi * 16);
      s = __builtin_amdgcn_mfma_f32_32x32x16_bf16(a, qf[dk], s, 0, 0, 0);
    }
    __builtin_amdgcn_s_setprio(0);
    // lane holds, for q=ql: k' = 32h + (r&3) + 8*(r>>2) + 4*hi, r=0..15

    // ---- in-register online softmax (per-wave m,l over its k') ----
    float x0 = fmaxf(fmaxf(s[0], s[1]), fmaxf(s[2], s[3]));
    float x1 = fmaxf(fmaxf(s[4], s[5]), fmaxf(s[6], s[7]));
    float x2 = fmaxf(fmaxf(s[8], s[9]), fmaxf(s[10], s[11]));
    float x3 = fmaxf(fmaxf(s[12], s[13]), fmaxf(s[14], s[15]));
    float pm = fmaxf(fmaxf(x0, x1), fmaxf(x2, x3));
    pm = fmaxf(pm, __shfl_xor(pm, 32, 64));

    if (!__all(pm <= m_r + 8.0f)) {   // defer-max (T13)
      const float mnew = fmaxf(m_r, pm);
      const float alpha = __builtin_amdgcn_exp2f(m_r - mnew);
      l_r *= alpha;
#pragma unroll
      for (int dt = 0; dt < 4; ++dt) o[dt] *= alpha;
      m_r = mnew;
    }

    float p[16];
#pragma unroll
    for (int j = 0; j < 16; ++j) p[j] = __builtin_amdgcn_exp2f(s[j] - m_r);
    {
      float r0 = 0.f, r1 = 0.f, r2 = 0.f, r3 = 0.f;
#pragma unroll
      for (int j = 0; j < 4; ++j) {
        r0 += p[j]; r1 += p[4 + j]; r2 += p[8 + j]; r3 += p[12 + j];
      }
      float rsum = (r0 + r1) + (r2 + r3);
      l_r += rsum + __shfl_xor(rsum, 32, 64);
    }

    // ---- pack P to bf16 + half-exchange with lane^32 -> PV B-fragments ----
    uint32_t own[4][2];
#pragma unroll
    for (int mm = 0; mm < 4; ++mm) {
      own[mm][0] = pk2(p[4 * mm + 0], p[4 * mm + 1]);
      own[mm][1] = pk2(p[4 * mm + 2], p[4 * mm + 3]);
    }
    uint32_t rcv[2][2];
#pragma unroll
    for (int jj = 0; jj < 2; ++jj)
#pragma unroll
      for (int e = 0; e < 2; ++e) {
        uint32_t sel = hi ? own[2 * jj][e] : own[2 * jj + 1][e];
        rcv[jj][e] = (uint32_t)__shfl_xor((int)sel, 32, 64);
      }
    bf16x8 pb[2];
#pragma unroll
    for (int ks = 0; ks < 2; ++ks) {
      union { uint32_t u[4]; bf16x8 v; } tt;
      tt.u[0] = hi ? rcv[ks][0] : own[2 * ks][0];
      tt.u[1] = hi ? rcv[ks][1] : own[2 * ks][1];
      tt.u[2] = hi ? own[2 * ks + 1][0] : rcv[ks][0];
      tt.u[3] = hi ? own[2 * ks + 1][1] : rcv[ks][1];
      pb[ks] = tt.v;
    }

    // ---- PV as O^T = V^T·P^T over this wave's k' ----
    __builtin_amdgcn_s_setprio(1);
#pragma unroll
    for (int dt = 0; dt < 4; ++dt) {
      const uint32_t vbase =
          (uint32_t)(VTOFF + (dt * 32 + ql) * VSTRIDE + h * 64 + hi * 16);
#pragma unroll
      for (int ks = 0; ks < 2; ++ks) {
        bf16x8 a = *(const bf16x8*)(smem + vbase + ks * 32);
        o[dt] = __builtin_amdgcn_mfma_f32_32x32x16_bf16(a, pb[ks], o[dt], 0, 0, 0);
      }
    }
    __builtin_amdgcn_s_setprio(0);

    __syncthreads();             // all waves done reading this tile
    if (t < nt - 1) {
      STAGE(kvbase + (t + 1) * KVBLK)
      __syncthreads();           // staged tile visible
    }
  }

  // ---- merge the two k-subset partials (w <-> w^2) in LDS ----
  char* xch = smem + qw * 16896;
  if (h) {                       // k-half 1: writer
#pragma unroll
    for (int dt = 0; dt < 4; ++dt) {
#pragma unroll
      for (int q2 = 0; q2 < 4; ++q2) {
        float4 v;
        v.x = o[dt][4 * q2 + 0]; v.y = o[dt][4 * q2 + 1];
        v.z = o[dt][4 * q2 + 2]; v.w = o[dt][4 * q2 + 3];
        *(float4*)(xch + (dt * 4 + q2) * 1024 + lane * 16) = v;
      }
    }
    *(float2*)(xch + 16384 + lane * 8) = make_float2(m_r, l_r);
  }
  __syncthreads();
  if (!h) {                      // k-half 0: merger + storer
    const float2 ml1v = *(const float2*)(xch + 16384 + lane * 8);
    const float M = fmaxf(m_r, ml1v.x);
    const float w0 = __builtin_amdgcn_exp2f(m_r - M);
    const float w1 = __builtin_amdgcn_exp2f(ml1v.x - M);
    const float lsum = l_r * w0 + ml1v.y * w1;
    if (SPLIT) {
      float* Op = kvh ? O1 : O0;
      float2* ml = kvh ? ml1 : ml0;
      const int rowb = b * Sn + qg;
      float* orow = Op + (size_t)rowb * Dn;
#pragma unroll
      for (int dt = 0; dt < 4; ++dt) {
#pragma unroll
        for (int q2 = 0; q2 < 4; ++q2) {
          const float4 o1v =
              *(const float4*)(xch + (dt * 4 + q2) * 1024 + lane * 16);
          float4 v;
          v.x = o[dt][4 * q2 + 0] * w0 + o1v.x * w1;
          v.y = o[dt][4 * q2 + 1] * w0 + o1v.y * w1;
          v.z = o[dt][4 * q2 + 2] * w0 + o1v.z * w1;
          v.w = o[dt][4 * q2 + 3] * w0 + o1v.w * w1;
          *(float4*)(orow + dt * 32 + q2 * 8 + hi * 4) = v;
        }
      }
      ml[rowb] = make_float2(M, lsum);   // uniform across hi; dup write benign
    } else {
      const float inv = 1.0f / lsum;
      const float s0 = w0 * inv, s1 = w1 * inv;
      float* orow = O0 + (size_t)(b * Sn + qg) * Dn;
#pragma unroll
      for (int dt = 0; dt < 4; ++dt) {
#pragma unroll
        for (int q2 = 0; q2 < 4; ++q2) {
          const float4 o1v =
              *(const float4*)(xch + (dt * 4 + q2) * 1024 + lane * 16);
          float4 v;
          v.x = o[dt][4 * q2 + 0] * s0 + o1v.x * s1;
          v.y = o[dt][4 * q2 + 1] * s0 + o1v.y * s1;
          v.z = o[dt][4 * q2 + 2] * s0 + o1v.z * s1;
          v.w = o[dt][4 * q2 + 3] * s0 + o1v.w * s1;
          *(float4*)(orow + dt * 32 + q2 * 8 + hi * 4) = v;
        }
      }
    }
  }
}

__global__ __launch_bounds__(256) void attn_combine(
    float* __restrict__ O, const float* __restrict__ O1,
    const float2* __restrict__ ml0, const float2* __restrict__ ml1) {
  const int e = blockIdx.x * 256 + threadIdx.x;   // one float4 per thread
  const int row = e >> 5;
  const float2 a = ml0[row];
  const float2 bb = ml1[row];
  const float M = fmaxf(a.x, bb.x);
  const float w0 = __builtin_amdgcn_exp2f(a.x - M);
  const float w1 = __builtin_amdgcn_exp2f(bb.x - M);
  const float inv = 1.0f / (w0 * a.y + w1 * bb.y);
  const float s0 = w0 * inv, s1 = w1 * inv;
  f32x4 o0 = ((const f32x4*)O)[e];
  f32x4 o1 = ((const f32x4*)O1)[e];
  ((f32x4*)O)[e] = o0 * s0 + o1 * s1;
}

extern "C" void kernel_launch(void* const* d_in, const int* in_sizes, int n_in,
                              void* d_out, int out_size, void* d_ws, size_t ws_size,
                              hipStream_t stream) {
  (void)in_sizes; (void)n_in; (void)out_size;
  const float* Q = (const float*)d_in[0];
  const float* K = (const float*)d_in[1];
  const float* V = (const float*)d_in[2];
  float* O = (float*)d_out;

  const size_t nO = (size_t)Bn * Sn * Dn;
  const size_t needB = nO * 4 + (size_t)Bn * Sn * 8 * 2;

  if (ws_size >= needB) {
    float* O1 = (float*)d_ws;
    float2* ml0 = (float2*)((char*)d_ws + nO * 4);
    float2* ml1 = ml0 + (size_t)Bn * Sn;
    dim3 grid(Sn / QBLK, Bn, 2);
    attn_fwd<true><<<grid, dim3(NTHR, 1, 1), 0, stream>>>(Q, K, V, O, O1, ml0, ml1);
    const int nblk = (int)(nO / 4 / 256);
    attn_combine<<<nblk, 256, 0, stream>>>(O, O1, ml0, ml1);
  } else {
    dim3 grid(Sn / QBLK, Bn, 1);
    attn_fwd<false><<<grid, dim3(NTHR, 1, 1), 0, stream>>>(Q, K, V, O, nullptr,
                                                           nullptr, nullptr);
  }
}

// Round 11
// 112.692 us; speedup vs baseline: 2.2748x; 2.2748x over previous
//
#include <hip/hip_runtime.h>
#include <stdint.h>

#define Bn 16
#define Sn 2048
#define Dn 128
#define QBLK 64
#define KVBLK 64
#define NTHR 256
#define NT (Sn / KVBLK)

typedef __attribute__((ext_vector_type(4))) float f32x4;
typedef __attribute__((ext_vector_type(16))) float f32x16;
typedef __attribute__((ext_vector_type(8))) short bf16x8;   // 8 bf16 = 4 VGPRs
typedef __attribute__((ext_vector_type(2))) unsigned int u32x2;

// LDS:
//  K   : [64] rows stride 264 B, byte(k,d) = k*264 + 2d  (2-way banks, free)  16896 B
//  xch : epilogue-only exchange, qw*16896 .. +16896 (overlays K region+tail)
#define KSTRIDE 264
#define SMEM_BYTES 33792

__device__ __forceinline__ uint32_t f2bf_u(float f) {   // fp32 -> bf16, round-nearest-away
  return (__float_as_uint(f) + 0x8000u) >> 16;
}
__device__ __forceinline__ uint32_t pk2(float a, float b) {
  return f2bf_u(a) | (f2bf_u(b) << 16);
}

__global__ __launch_bounds__(NTHR, 2) void attn_fwd(
    const float* __restrict__ Q, const float* __restrict__ K,
    const float* __restrict__ V, float* __restrict__ O) {
  __shared__ uint4 smem_[SMEM_BYTES / 16];
  char* smem = (char*)smem_;

  const int tid = threadIdx.x;
  const int lane = tid & 63;
  const int w = tid >> 6;        // wave 0..3
  const int qw = w & 1;          // q sub-tile (32 rows)
  const int h = w >> 1;          // k sub-range of tile (32 rows)
  const int hi = lane >> 5;      // half-wave 0/1
  const int ql = lane & 31;      // q / k-row / d-row selector

  // XCD-aware swizzle: consecutive blockIdx round-robin XCDs (i&7); give each
  // XCD only 2 batches so K+V working set (4 MB) ~ one XCD L2.
  const int i = blockIdx.x;
  const int j = i >> 3;
  const int b = (i & 7) + 8 * (j & 1);
  const int q0 = (j >> 1) * QBLK;
  const int qg = q0 + qw * 32 + ql;

  // ---- Q in registers: B-operand of swapped QK^T. col=q=lane&31, kd=8*hi+jj ----
  const float qscale = 0.08838834764831845f * 1.44269504088896340736f; // 1/sqrt(128)*log2e
  bf16x8 qf[8];
  {
    const float* qrow = Q + (size_t)(b * Sn + qg) * Dn;
#pragma unroll
    for (int dk = 0; dk < 8; ++dk) {
      const int d0 = dk * 16 + hi * 8;
      const float4 a = *(const float4*)(qrow + d0);
      const float4 d = *(const float4*)(qrow + d0 + 4);
      bf16x8 q8;
      q8[0] = (short)f2bf_u(a.x * qscale); q8[1] = (short)f2bf_u(a.y * qscale);
      q8[2] = (short)f2bf_u(a.z * qscale); q8[3] = (short)f2bf_u(a.w * qscale);
      q8[4] = (short)f2bf_u(d.x * qscale); q8[5] = (short)f2bf_u(d.y * qscale);
      q8[6] = (short)f2bf_u(d.z * qscale); q8[7] = (short)f2bf_u(d.w * qscale);
      qf[dk] = q8;
    }
  }

  f32x16 o[4];
#pragma unroll
  for (int dt = 0; dt < 4; ++dt) {
#pragma unroll
    for (int jj = 0; jj < 16; ++jj) o[dt][jj] = 0.f;
  }
  float m_r = -1.0e30f, l_r = 0.f;

  const float4* Kg4 = (const float4*)(K + (size_t)b * Sn * Dn);
  const float* Vg_base = V + (size_t)b * Sn * Dn;

  for (int t = 0; t < NT; ++t) {
    const int kv = t * KVBLK;
    const int kvk = kv + 32 * h;       // this wave's 32-row k slice

    __syncthreads();   // prev tile's K reads done; region free for staging

    // ---- stage K tile: fp32 global (float4, coalesced) -> bf16 LDS ----
    {
      const int kvrow4 = kv * (Dn / 4);
#pragma unroll
      for (int it = 0; it < 8; ++it) {
        const int gr = it * NTHR + tid;
        const int k = gr >> 5, dg = gr & 31;
        float4 kvv = Kg4[kvrow4 + k * 32 + dg];
        u32x2 wv;
        wv.x = pk2(kvv.x, kvv.y);
        wv.y = pk2(kvv.z, kvv.w);
        *(u32x2*)(smem + k * KSTRIDE + dg * 8) = wv;
      }
    }
    __syncthreads();

    // ---- issue ALL V fragment loads (direct global, coalesced 2x128B/instr);
    //      latency hides under QK^T + softmax ----
    float vf[8][8];
    {
      const float* vb = Vg_base + (size_t)kvk * Dn + 8 * hi * Dn + ql;
#pragma unroll
      for (int dt = 0; dt < 4; ++dt)
#pragma unroll
        for (int ks = 0; ks < 2; ++ks)
#pragma unroll
          for (int jj = 0; jj < 8; ++jj)
            vf[dt * 2 + ks][jj] = vb[(ks * 16 + jj) * Dn + dt * 32];
    }

    // ---- swapped QK^T: S^T[k'][q] over this wave's 32-row k-subset ----
    f32x16 s;
#pragma unroll
    for (int jj = 0; jj < 16; ++jj) s[jj] = 0.f;
    __builtin_amdgcn_s_setprio(1);
#pragma unroll
    for (int dk = 0; dk < 8; ++dk) {
      bf16x8 a = *(const bf16x8*)(smem + (32 * h + ql) * KSTRIDE +
                                  dk * 32 + hi * 16);
      s = __builtin_amdgcn_mfma_f32_32x32x16_bf16(a, qf[dk], s, 0, 0, 0);
    }
    __builtin_amdgcn_s_setprio(0);
    // lane holds, for q=ql: k' = 32h + (r&3) + 8*(r>>2) + 4*hi, r=0..15

    // ---- in-register online softmax (per-wave m,l over its k') ----
    float x0 = fmaxf(fmaxf(s[0], s[1]), fmaxf(s[2], s[3]));
    float x1 = fmaxf(fmaxf(s[4], s[5]), fmaxf(s[6], s[7]));
    float x2 = fmaxf(fmaxf(s[8], s[9]), fmaxf(s[10], s[11]));
    float x3 = fmaxf(fmaxf(s[12], s[13]), fmaxf(s[14], s[15]));
    float pm = fmaxf(fmaxf(x0, x1), fmaxf(x2, x3));
    pm = fmaxf(pm, __shfl_xor(pm, 32, 64));

    if (!__all(pm <= m_r + 8.0f)) {   // defer-max (T13)
      const float mnew = fmaxf(m_r, pm);
      const float alpha = __builtin_amdgcn_exp2f(m_r - mnew);
      l_r *= alpha;
#pragma unroll
      for (int dt = 0; dt < 4; ++dt) o[dt] *= alpha;
      m_r = mnew;
    }

#pragma unroll
    for (int jj = 0; jj < 16; ++jj) s[jj] = __builtin_amdgcn_exp2f(s[jj] - m_r);
    {
      float r0 = 0.f, r1 = 0.f, r2 = 0.f, r3 = 0.f;
#pragma unroll
      for (int jj = 0; jj < 4; ++jj) {
        r0 += s[jj]; r1 += s[4 + jj]; r2 += s[8 + jj]; r3 += s[12 + jj];
      }
      float rsum = (r0 + r1) + (r2 + r3);
      l_r += rsum + __shfl_xor(rsum, 32, 64);
    }

    // ---- pack P to bf16 + half-exchange with lane^32 -> PV B-fragments ----
    uint32_t own[4][2];
#pragma unroll
    for (int mm = 0; mm < 4; ++mm) {
      own[mm][0] = pk2(s[4 * mm + 0], s[4 * mm + 1]);
      own[mm][1] = pk2(s[4 * mm + 2], s[4 * mm + 3]);
    }
    uint32_t rcv[2][2];
#pragma unroll
    for (int jj = 0; jj < 2; ++jj)
#pragma unroll
      for (int e = 0; e < 2; ++e) {
        uint32_t sel = hi ? own[2 * jj][e] : own[2 * jj + 1][e];
        rcv[jj][e] = (uint32_t)__shfl_xor((int)sel, 32, 64);
      }
    bf16x8 pb[2];
#pragma unroll
    for (int ks = 0; ks < 2; ++ks) {
      union { uint32_t u[4]; bf16x8 v; } tt;
      tt.u[0] = hi ? rcv[ks][0] : own[2 * ks][0];
      tt.u[1] = hi ? rcv[ks][1] : own[2 * ks][1];
      tt.u[2] = hi ? own[2 * ks + 1][0] : rcv[ks][0];
      tt.u[3] = hi ? own[2 * ks + 1][1] : rcv[ks][1];
      pb[ks] = tt.v;
    }

    // ---- PV as O^T = V^T·P^T: A-frags converted from the hoisted V loads ----
    __builtin_amdgcn_s_setprio(1);
#pragma unroll
    for (int dt = 0; dt < 4; ++dt) {
#pragma unroll
      for (int ks = 0; ks < 2; ++ks) {
        const int f = dt * 2 + ks;
        union { uint32_t u[4]; bf16x8 v; } tv;
        tv.u[0] = pk2(vf[f][0], vf[f][1]);
        tv.u[1] = pk2(vf[f][2], vf[f][3]);
        tv.u[2] = pk2(vf[f][4], vf[f][5]);
        tv.u[3] = pk2(vf[f][6], vf[f][7]);
        o[dt] = __builtin_amdgcn_mfma_f32_32x32x16_bf16(tv.v, pb[ks], o[dt], 0, 0, 0);
      }
    }
    __builtin_amdgcn_s_setprio(0);
  }

  // ---- merge the two k-subset partials (w <-> w^2) in LDS, then store ----
  __syncthreads();
  char* xch = smem + qw * 16896;
  if (h) {                       // k-half 1: writer
#pragma unroll
    for (int dt = 0; dt < 4; ++dt) {
#pragma unroll
      for (int q2 = 0; q2 < 4; ++q2) {
        float4 v;
        v.x = o[dt][4 * q2 + 0]; v.y = o[dt][4 * q2 + 1];
        v.z = o[dt][4 * q2 + 2]; v.w = o[dt][4 * q2 + 3];
        *(float4*)(xch + (dt * 4 + q2) * 1024 + lane * 16) = v;
      }
    }
    *(float2*)(xch + 16384 + lane * 8) = make_float2(m_r, l_r);
  }
  __syncthreads();
  if (!h) {                      // k-half 0: merger + storer
    const float2 ml1v = *(const float2*)(xch + 16384 + lane * 8);
    const float M = fmaxf(m_r, ml1v.x);
    const float w0 = __builtin_amdgcn_exp2f(m_r - M);
    const float w1 = __builtin_amdgcn_exp2f(ml1v.x - M);
    const float inv = 1.0f / (l_r * w0 + ml1v.y * w1);
    const float s0 = w0 * inv, s1 = w1 * inv;
    float* orow = O + (size_t)(b * Sn + qg) * Dn;
#pragma unroll
    for (int dt = 0; dt < 4; ++dt) {
#pragma unroll
      for (int q2 = 0; q2 < 4; ++q2) {
        const float4 o1v =
            *(const float4*)(xch + (dt * 4 + q2) * 1024 + lane * 16);
        float4 v;
        v.x = o[dt][4 * q2 + 0] * s0 + o1v.x * s1;
        v.y = o[dt][4 * q2 + 1] * s0 + o1v.y * s1;
        v.z = o[dt][4 * q2 + 2] * s0 + o1v.z * s1;
        v.w = o[dt][4 * q2 + 3] * s0 + o1v.w * s1;
        *(float4*)(orow + dt * 32 + q2 * 8 + hi * 4) = v;
      }
    }
  }
}

extern "C" void kernel_launch(void* const* d_in, const int* in_sizes, int n_in,
                              void* d_out, int out_size, void* d_ws, size_t ws_size,
                              hipStream_t stream) {
  (void)in_sizes; (void)n_in; (void)d_ws; (void)ws_size; (void)out_size;
  const float* Q = (const float*)d_in[0];
  const float* K = (const float*)d_in[1];
  const float* V = (const float*)d_in[2];
  float* O = (float*)d_out;
  attn_fwd<<<dim3((Sn / QBLK) * Bn, 1, 1), dim3(NTHR, 1, 1), 0, stream>>>(Q, K, V, O);
}